// Round 11
// baseline (601.043 us; speedup 1.0000x reference)
//
#include <hip/hip_runtime.h>

#define NN 40000
#define EE 512000
#define NB 157      // dst buckets per branch: d>>8, 256 nodes per bucket
#define BCAP 8000   // pairs per bucket (avg 3277, std ~57); 2*157*8000*8 = 20.1 MB <= |Hb2|

typedef unsigned short u16;
typedef __attribute__((ext_vector_type(8))) short bf16x8;
typedef __attribute__((ext_vector_type(4))) float f32x4;

__device__ __forceinline__ float bf2f(u16 u) { return __uint_as_float(((unsigned)u) << 16); }
__device__ __forceinline__ u16 f2bf(float f) {
    unsigned u = __float_as_uint(f);
    u += 0x7FFFu + ((u >> 16) & 1u);
    return (u16)(u >> 16);
}
__device__ __forceinline__ unsigned pack2(float a, float b) {
    return (unsigned)f2bf(a) | ((unsigned)f2bf(b) << 16);
}
__device__ __forceinline__ float lrelu(float t) { return t > 0.f ? t : 0.2f * t; }

// ---------------- dtype detection ----------------
__global__ __launch_bounds__(256) void detect_k(const u16* __restrict__ x, int* __restrict__ flag) {
    int t = threadIdx.x;
    int cnt = 0;
    for (int j = 0; j < 8; ++j) {
        float v = bf2f(x[(t * 8 + j) * 2]);
        float a = fabsf(v);
        if (a >= 0.00390625f && a <= 256.0f) cnt++;
    }
    __shared__ int sh[256];
    sh[t] = cnt;
    __syncthreads();
    for (int off = 128; off > 0; off >>= 1) {
        if (t < off) sh[t] += sh[t + off];
        __syncthreads();
    }
    if (t == 0) flag[0] = (sh[0] > 1024) ? 1 : 0;
}

// ---------------- weight conversion ----------------
struct CvtArgs {
    const void* src[28];
    float* dst[28];
    int n[28];
};

__global__ __launch_bounds__(256) void cvt_k(CvtArgs a, const int* __restrict__ flag) {
    int b = blockIdx.x;
    int n = a.n[b];
    float* d = a.dst[b];
    if (*flag) {
        const u16* p = (const u16*)a.src[b];
        for (int i = threadIdx.x; i < n; i += 256) d[i] = bf2f(p[i]);
    } else {
        const float* p = (const float*)a.src[b];
        for (int i = threadIdx.x; i < n; i += 256) d[i] = p[i];
    }
}

// transpose the 3 GAT weight matrices to bf16 Wt[n][k] for MFMA B-operand
__global__ __launch_bounds__(256) void wtb_k(const float* __restrict__ wcvt, u16* __restrict__ Wtb) {
    int l = blockIdx.x;
    const float* W = wcvt + l * 16640;  // W_l at stride 16384+128+128
    u16* D = Wtb + l * 16384;
    for (int i = threadIdx.x; i < 16384; i += 256) {
        int n = i >> 7, k = i & 127;
        D[i] = f2bf(W[k * 128 + n]);
    }
}

// ---------------- two-phase bucketed CSR build, both branches fused ----------------
__global__ __launch_bounds__(256) void bucket_k(const int* __restrict__ ei1,
                                                const int* __restrict__ ei2,
                                                int* __restrict__ gcnt,
                                                int2* __restrict__ buf) {
    __shared__ int lh[NB];
    __shared__ int lbase[NB];
    __shared__ int loff[NB];
    int branch = blockIdx.x >= 500;
    int blk = blockIdx.x - (branch ? 500 : 0);
    const int* ei = branch ? ei2 : ei1;
    int gb0 = branch * NB;
    int tid = threadIdx.x;
    for (int i = tid; i < NB; i += 256) lh[i] = 0;
    __syncthreads();
    int e0 = blk * 1024 + tid;
    int sv[4], dv[4], bv[4];
#pragma unroll
    for (int j = 0; j < 4; ++j) {
        int e = e0 + j * 256;
        int d = ei[EE + e];
        int s = ei[e];
        if ((unsigned)d >= NN) d = -1;   // drop invalid dst
        if ((unsigned)s >= NN) s = 0;    // sanitize invalid src
        dv[j] = d;
        sv[j] = s;
        bv[j] = d >> 8;
        if (d >= 0 && (unsigned)bv[j] < NB) atomicAdd(&lh[bv[j]], 1);
        else dv[j] = -1;
    }
    __syncthreads();
    for (int i = tid; i < NB; i += 256) {
        int c = lh[i];
        lbase[i] = c ? atomicAdd(&gcnt[gb0 + i], c) : 0;
        loff[i] = 0;
    }
    __syncthreads();
#pragma unroll
    for (int j = 0; j < 4; ++j) {
        if (dv[j] >= 0) {
            int b = bv[j];
            int p = lbase[b] + atomicAdd(&loff[b], 1);
            if ((unsigned)p < BCAP) buf[(size_t)(gb0 + b) * BCAP + p] = (int2){sv[j], dv[j]};
        }
    }
}

__global__ __launch_bounds__(256) void build_k(const int* __restrict__ gcnt,
                                               const int2* __restrict__ buf,
                                               int* __restrict__ fill,
                                               int* __restrict__ csrc) {
    __shared__ int lf[256];
    int branch = blockIdx.x >= NB;
    int b = blockIdx.x - (branch ? NB : 0);
    int tid = threadIdx.x;
    lf[tid] = 0;
    __syncthreads();
    int n = gcnt[branch * NB + b];
    if (n < 0) n = 0;
    if (n > BCAP) n = BCAP;
    int d0 = b << 8;
    size_t soff = (size_t)branch * NN;
    const int2* bp = buf + (size_t)(branch * NB + b) * BCAP;
    for (int i = tid; i < n; i += 256) {
        int2 p = bp[i];
        unsigned loc = (unsigned)(p.y - d0);
        if (loc < 256u && (unsigned)p.y < NN && (unsigned)p.x < NN) {
            int pos = atomicAdd(&lf[loc], 1);
            if ((unsigned)pos < 64u) csrc[(soff + p.y) * 64 + pos] = p.x;
        }
    }
    __syncthreads();
    int d = d0 + tid;
    if (d < NN) fill[soff + d] = lf[tid];  // agg_k clamps to 64
}

// ---------------- MFMA matmul + fused BN(precomputed consts) + fused es/ed ----------------
// Block geometry: 128 threads (2 waves), 32 rows per block, grid 2500 (blocks
// [0,1250)=branch0). ~10 blocks/CU resident (vs 4.9 at the old 256t/64row geometry)
// so stage/barrier/compute phases of independent blocks overlap. Per-wave inner
// code (16-row m-tile, fragments, MFMA, es/ed reduce, epilogue) is unchanged.
__global__ __launch_bounds__(128) void matmul_mfma_k(const void* __restrict__ X1,
                                                     const void* __restrict__ X2,
                                                     const u16* __restrict__ Abase,
                                                     int mode,
                                                     const int* __restrict__ flag,
                                                     const float* __restrict__ bnc,
                                                     const u16* __restrict__ Wtb,
                                                     const float* __restrict__ asf,
                                                     const float* __restrict__ adf,
                                                     u16* __restrict__ Hbase,
                                                     float* __restrict__ es, float* __restrict__ ed) {
    __shared__ u16 Xs[32 * 136];
    __shared__ float scs[128], shs[128];
    int tid = threadIdx.x;
    int branch = blockIdx.x >= 1250;
    int blk = blockIdx.x - (branch ? 1250 : 0);
    size_t boff = (size_t)branch * NN;
    size_t row0 = (size_t)blk * 32;
    if (mode == 1) {
        scs[tid] = bnc[branch * 256 + tid];
        shs[tid] = bnc[branch * 256 + 128 + tid];
        __syncthreads();
        const uint2* X2p = reinterpret_cast<const uint2*>(Abase + (boff + row0) * 128);
        for (int i = tid; i < 1024; i += 128) {
            uint2 p = X2p[i];
            int r = i >> 5, c0 = (i & 31) * 4;
            float v0 = fmaf(bf2f((u16)(p.x & 0xffffu)), scs[c0], shs[c0]);
            float v1 = fmaf(bf2f((u16)(p.x >> 16)), scs[c0 + 1], shs[c0 + 1]);
            float v2 = fmaf(bf2f((u16)(p.y & 0xffffu)), scs[c0 + 2], shs[c0 + 2]);
            float v3 = fmaf(bf2f((u16)(p.y >> 16)), scs[c0 + 3], shs[c0 + 3]);
            v0 = v0 > 0.f ? v0 : 0.f; v1 = v1 > 0.f ? v1 : 0.f;
            v2 = v2 > 0.f ? v2 : 0.f; v3 = v3 > 0.f ? v3 : 0.f;
            unsigned* dst = (unsigned*)(Xs + r * 136 + c0);
            dst[0] = pack2(v0, v1);
            dst[1] = pack2(v2, v3);
        }
    } else {
        const void* Xv = branch ? X2 : X1;
        if (*flag) {
            const uint2* X2p = reinterpret_cast<const uint2*>((const u16*)Xv + row0 * 128);
            for (int i = tid; i < 1024; i += 128) {
                uint2 p = X2p[i];
                int r = i >> 5, c0 = (i & 31) * 4;
                unsigned* dst = (unsigned*)(Xs + r * 136 + c0);
                dst[0] = p.x;
                dst[1] = p.y;
            }
        } else {
            const float4* X4 = reinterpret_cast<const float4*>((const float*)Xv + row0 * 128);
            for (int i = tid; i < 1024; i += 128) {
                float4 v = X4[i];
                int r = i >> 5, c0 = (i & 31) * 4;
                unsigned* dst = (unsigned*)(Xs + r * 136 + c0);
                dst[0] = pack2(v.x, v.y);
                dst[1] = pack2(v.z, v.w);
            }
        }
    }
    __syncthreads();
    int w = tid >> 6, l = tid & 63;
    int q = l >> 4, c = l & 15;
    int mrow = w * 16;
    f32x4 acc[8];
#pragma unroll
    for (int t = 0; t < 8; ++t) acc[t] = (f32x4){0.f, 0.f, 0.f, 0.f};
#pragma unroll
    for (int ks = 0; ks < 4; ++ks) {
        int k0 = ks * 32;
        bf16x8 afrag = *(const bf16x8*)(Xs + (mrow + c) * 136 + k0 + q * 8);
#pragma unroll
        for (int t = 0; t < 8; ++t) {
            bf16x8 bfrag = *(const bf16x8*)(Wtb + (t * 16 + c) * 128 + k0 + q * 8);
            acc[t] = __builtin_amdgcn_mfma_f32_16x16x32_bf16(afrag, bfrag, acc[t], 0, 0, 0);
        }
    }
    // es/ed: per-head partial sums over this lane's cols, then 16-lane xor-reduce
    float esp[4][4] = {}, edp[4][4] = {};
#pragma unroll
    for (int t = 0; t < 8; ++t) {
        float av = asf[t * 16 + c], dv = adf[t * 16 + c];
        int h = t >> 1;
#pragma unroll
        for (int r = 0; r < 4; ++r) {
            esp[h][r] = fmaf(acc[t][r], av, esp[h][r]);
            edp[h][r] = fmaf(acc[t][r], dv, edp[h][r]);
        }
    }
#pragma unroll
    for (int h = 0; h < 4; ++h)
#pragma unroll
        for (int r = 0; r < 4; ++r) {
            esp[h][r] += __shfl_xor(esp[h][r], 1, 64);
            esp[h][r] += __shfl_xor(esp[h][r], 2, 64);
            esp[h][r] += __shfl_xor(esp[h][r], 4, 64);
            esp[h][r] += __shfl_xor(esp[h][r], 8, 64);
            edp[h][r] += __shfl_xor(edp[h][r], 1, 64);
            edp[h][r] += __shfl_xor(edp[h][r], 2, 64);
            edp[h][r] += __shfl_xor(edp[h][r], 4, 64);
            edp[h][r] += __shfl_xor(edp[h][r], 8, 64);
        }
    if (c < 4) {
#pragma unroll
        for (int r = 0; r < 4; ++r) {
            size_t grow = boff + row0 + mrow + q * 4 + r;
            es[grow * 4 + c] = esp[c][r];
            ed[grow * 4 + c] = edp[c][r];
        }
    }
    // store C: scatter bf16 into LDS (reuse Xs as unpadded 32x128), then coalesced copy
    __syncthreads();
    u16* Cs = Xs;
#pragma unroll
    for (int t = 0; t < 8; ++t)
#pragma unroll
        for (int r = 0; r < 4; ++r)
            Cs[(mrow + q * 4 + r) * 128 + t * 16 + c] = f2bf(acc[t][r]);
    __syncthreads();
    uint2* yp = (uint2*)(Hbase + (boff + row0) * 128);
    const uint2* cs2 = (const uint2*)Cs;
    for (int i = tid; i < 1024; i += 128) yp[i] = cs2[i];
}

// ---------------- GAT aggregation + fused BN-stat accumulation; both branches ----------------
// Round-4 structure (verified fastest at 72 us): batched 8-wide loops with SEPARATE
// load phases (8x csrc, then 8x es+exp, then 8x hb) so the compiler keeps ~8 loads
// in flight (high MLP), plus scalar tail. Do NOT merge per-j chains under branches.
__global__ __launch_bounds__(256) void agg_k(const u16* __restrict__ hb, const float* __restrict__ es,
                                             const float* __restrict__ ed, const int* __restrict__ fill,
                                             const int* __restrict__ csrc, u16* __restrict__ Ab,
                                             float* __restrict__ bktbase, int l) {
    __shared__ float ss[512], qq[512];
    int gwid = (blockIdx.x * 256 + threadIdx.x) >> 6;  // 0..79999
    int branch = gwid >= NN;
    size_t srow = branch ? (size_t)NN : 0;
    int lane = threadIdx.x & 63;
    int deg = fill[gwid];
    if (deg > 64) deg = 64;
    if (deg < 0) deg = 0;
    size_t rs = (size_t)gwid * 64;
    int head = lane >> 4;
    float edn = ed[gwid * 4 + head];
    float acc0, acc1, den;
    {
        float w = __expf(lrelu(es[gwid * 4 + head] + edn));
        den = w;
        unsigned pv = ((const unsigned*)(hb + (size_t)gwid * 128))[lane];
        acc0 = w * bf2f((u16)(pv & 0xffffu));
        acc1 = w * bf2f((u16)(pv >> 16));
    }
    int i = 0;
    for (; i + 8 <= deg; i += 8) {
        int sv[8];
#pragma unroll
        for (int j = 0; j < 8; ++j) sv[j] = csrc[rs + i + j];
        float wv[8];
#pragma unroll
        for (int j = 0; j < 8; ++j) wv[j] = __expf(lrelu(es[(srow + sv[j]) * 4 + head] + edn));
        unsigned pv[8];
#pragma unroll
        for (int j = 0; j < 8; ++j) pv[j] = ((const unsigned*)(hb + (srow + sv[j]) * 128))[lane];
#pragma unroll
        for (int j = 0; j < 8; ++j) {
            den += wv[j];
            acc0 = fmaf(wv[j], bf2f((u16)(pv[j] & 0xffffu)), acc0);
            acc1 = fmaf(wv[j], bf2f((u16)(pv[j] >> 16)), acc1);
        }
    }
    for (; i < deg; ++i) {
        int s = csrc[rs + i];
        float w = __expf(lrelu(es[(srow + s) * 4 + head] + edn));
        den += w;
        unsigned pv = ((const unsigned*)(hb + (srow + s) * 128))[lane];
        acc0 = fmaf(w, bf2f((u16)(pv & 0xffffu)), acc0);
        acc1 = fmaf(w, bf2f((u16)(pv >> 16)), acc1);
    }
    float inv = 1.0f / den;
    float v0 = acc0 * inv, v1 = acc1 * inv;
    ((unsigned*)Ab)[(size_t)gwid * 64 + lane] = (unsigned)f2bf(v0) | ((unsigned)f2bf(v1) << 16);
    int w = threadIdx.x >> 6;
    ss[w * 128 + 2 * lane] = v0;      ss[w * 128 + 2 * lane + 1] = v1;
    qq[w * 128 + 2 * lane] = v0 * v0; qq[w * 128 + 2 * lane + 1] = v1 * v1;
    __syncthreads();
    int t = threadIdx.x;
    float* dst = bktbase + (branch * 3 + l) * 16384 + (blockIdx.x & 63) * 256;
    if (t < 128) {
        atomicAdd(&dst[t], ss[t] + ss[128 + t] + ss[256 + t] + ss[384 + t]);
    } else {
        int f = t - 128;
        atomicAdd(&dst[t], qq[f] + qq[128 + f] + qq[256 + f] + qq[384 + f]);
    }
}

// ---------------- BN consts for layer l, both branches (grid 2) ----------------
__global__ __launch_bounds__(256) void bnconst_k(const float* __restrict__ bktbase, int l,
                                                 const float* __restrict__ gam,
                                                 const float* __restrict__ bet,
                                                 float* __restrict__ bnc) {
    __shared__ float red[256];
    int b = blockIdx.x;
    const float* bkt = bktbase + (b * 3 + l) * 16384;
    int tid = threadIdx.x;
    float s = 0.f;
    for (int k = 0; k < 64; ++k) s += bkt[k * 256 + tid];
    red[tid] = s;
    __syncthreads();
    if (tid < 128) {
        float mu = red[tid] * (1.0f / NN);
        float var = red[128 + tid] * (1.0f / NN) - mu * mu;
        float sc_ = rsqrtf(var + 1e-5f) * gam[tid];
        bnc[b * 256 + tid] = sc_;
        bnc[b * 256 + 128 + tid] = bet[tid] - mu * sc_;
    }
}

// ---------------- pooling: score (both branches; no atomics) ----------------
__global__ __launch_bounds__(256) void pool_score_k(const u16* __restrict__ Ab,
                                                    const float* __restrict__ bnc,
                                                    const float* __restrict__ attw,
                                                    float* __restrict__ scw) {
    int tid = threadIdx.x;
    int gwid = (blockIdx.x * 256 + tid) >> 6;
    int branch = gwid >= NN;
    const float* bncp = bnc + branch * 256;
    int lane = tid & 63;
    int f0 = 2 * lane, f1 = 2 * lane + 1;
    unsigned pv = ((const unsigned*)Ab)[(size_t)gwid * 64 + lane];
    float v0 = fmaf(bf2f((u16)(pv & 0xffffu)), bncp[f0], bncp[128 + f0]); v0 = v0 > 0.f ? v0 : 0.f;
    float v1 = fmaf(bf2f((u16)(pv >> 16)), bncp[f1], bncp[128 + f1]);     v1 = v1 > 0.f ? v1 : 0.f;
    float v = v0 * attw[f0] + v1 * attw[f1];
    for (int off = 1; off < 64; off <<= 1) v += __shfl_xor(v, off, 64);
    if (lane == 0) scw[gwid] = __expf(v);
}

__device__ __forceinline__ int lower_bound_dev(const int* __restrict__ b, int n, int v) {
    int lo = 0, hi = n;
    while (lo < hi) {
        int mid = (lo + hi) >> 1;
        if (b[mid] < v) lo = mid + 1; else hi = mid;
    }
    return lo;
}

// ---------------- pooling: per-graph denominator (grid 128) ----------------
__global__ __launch_bounds__(256) void pool_den_k(const float* __restrict__ scw,
                                                  const int* __restrict__ batch1,
                                                  const int* __restrict__ batch2,
                                                  float* __restrict__ gden) {
    int branch = blockIdx.x >= 64;
    int g = blockIdx.x - (branch ? 64 : 0);
    const int* batch = branch ? batch2 : batch1;
    const float* sc = scw + (size_t)branch * NN;
    int tid = threadIdx.x;
    int start = lower_bound_dev(batch, NN, g);
    int end = lower_bound_dev(batch, NN, g + 1);
    __shared__ float sh[256];
    float s = 0.f;
    for (int i = start + tid; i < end; i += 256) s += sc[i];
    sh[tid] = s;
    __syncthreads();
    for (int off = 128; off > 0; off >>= 1) {
        if (tid < off) sh[tid] += sh[tid + off];
        __syncthreads();
    }
    if (tid == 0) gden[blockIdx.x] = (sh[0] > 1e-30f) ? sh[0] : 1e-30f;
}

// ---------------- pooling: weighted accumulation (grid 1250) ----------------
__global__ __launch_bounds__(256) void pool_accum2_k(const u16* __restrict__ Ab,
                                                     const float* __restrict__ scw,
                                                     const int* __restrict__ batch1,
                                                     const int* __restrict__ batch2,
                                                     const float* __restrict__ gden,
                                                     const float* __restrict__ bnc,
                                                     float* __restrict__ pooled) {
    __shared__ float wsh[64];
    __shared__ int gsh[64];
    int branch = blockIdx.x >= 625;
    int blk = blockIdx.x - (branch ? 625 : 0);
    const int* batch = branch ? batch2 : batch1;
    size_t boff = (size_t)branch * NN;
    int r0 = blk * 64;
    int tid = threadIdx.x;
    if (tid < 64) {
        int g = batch[r0 + tid];
        if ((unsigned)g >= 64) g = 0;
        gsh[tid] = g;
        wsh[tid] = scw[boff + r0 + tid] / gden[branch * 64 + g];
    }
    __syncthreads();
    const float* bncp = bnc + branch * 256;
    float* poolp = pooled + (size_t)branch * 8192;
    int f = tid & 127, half = tid >> 7;
    float bs = bncp[f], bb = bncp[128 + f];
    float racc = 0.f;
    int curg = gsh[half];
    for (int r = half; r < 64; r += 2) {
        int g = gsh[r];
        if (g != curg) {
            atomicAdd(&poolp[curg * 128 + f], racc);
            racc = 0.f;
            curg = g;
        }
        float v = fmaf(bf2f(Ab[(boff + r0 + r) * 128 + f]), bs, bb);
        v = v > 0.f ? v : 0.f;
        racc = fmaf(wsh[r], v, racc);
    }
    atomicAdd(&poolp[curg * 128 + f], racc);
}

// ---------------- head A (grid 128) ----------------
__global__ __launch_bounds__(256) void headA_k(const float* __restrict__ pooled,
                                               const float* __restrict__ fciw, const float* __restrict__ fcib,
                                               float* __restrict__ Tall) {
    __shared__ float Wl[6144];
    __shared__ float Pl[128];
    int tid = threadIdx.x;
    int g = blockIdx.x;
    for (int i = tid; i < 6144; i += 256) Wl[i] = fciw[i];
    if (tid < 128) Pl[tid] = pooled[g * 128 + tid];
    __syncthreads();
    if (tid < 48) {
        float s = fcib[tid];
        for (int k = 0; k < 128; ++k) s = fmaf(Pl[k], Wl[k * 48 + tid], s);
        Tall[g * 48 + tid] = s;
    }
}

// ---------------- head B ----------------
__global__ __launch_bounds__(256) void headB_k(const float* __restrict__ Tall,
                                               const float* __restrict__ gbi, const float* __restrict__ bbi,
                                               const float* __restrict__ fcw, const float* __restrict__ fcb,
                                               const float* __restrict__ fc1w, const float* __restrict__ fc1b,
                                               const float* __restrict__ gf1, const float* __restrict__ bf1,
                                               const float* __restrict__ fc2w, const float* __restrict__ fc2b,
                                               void* __restrict__ out, const int* __restrict__ flag) {
    __shared__ float T[6144];
    __shared__ float X[64 * 24];
    __shared__ float Y[64 * 12];
    __shared__ float st[192];
    __shared__ float st2[24];
    __shared__ float wl[576 + 288 + 12 + 12 + 12 + 12 + 48 + 48 + 1];
    float* fcw_l  = wl;
    float* fc1w_l = wl + 576;
    float* fcb_l  = wl + 864;
    float* fc1b_l = wl + 876;
    float* gf1_l  = wl + 888;
    float* bf1_l  = wl + 900;
    float* gbi_l  = wl + 912;
    float* bbi_l  = wl + 960;
    float* fc2b_l = wl + 1008;
    __shared__ float fc2w_l[12];
    int tid = threadIdx.x;
    for (int i = tid; i < 6144; i += 256) T[i] = Tall[i];
    for (int i = tid; i < 576; i += 256) fcw_l[i] = fcw[i];
    for (int i = tid; i < 288; i += 256) fc1w_l[i] = fc1w[i];
    if (tid < 12) {
        fcb_l[tid] = fcb[tid]; fc1b_l[tid] = fc1b[tid];
        gf1_l[tid] = gf1[tid]; bf1_l[tid] = bf1[tid];
        fc2w_l[tid] = fc2w[tid];
    }
    if (tid < 48) { gbi_l[tid] = gbi[tid]; bbi_l[tid] = bbi[tid]; }
    if (tid == 0) fc2b_l[0] = fc2b[0];
    __syncthreads();
    if (tid < 96) {
        int b = tid / 48, c = tid - b * 48;
        float s = 0.f, ss = 0.f;
        for (int g = 0; g < 64; ++g) { float v = T[b * 3072 + g * 48 + c]; s += v; ss += v * v; }
        float mu = s * (1.f / 64), var = ss * (1.f / 64) - mu * mu;
        float sc_ = rsqrtf(var + 1e-5f) * gbi_l[c];
        st[tid] = sc_;
        st[96 + tid] = bbi_l[c] - mu * sc_;
    }
    __syncthreads();
    for (int i = tid; i < 6144; i += 256) {
        int b = i / 3072, c = i % 48;
        int col = b * 48 + c;
        float v = fmaf(T[i], st[col], st[96 + col]);
        T[i] = v > 0.f ? v : 0.f;
    }
    __syncthreads();
    for (int idx = tid; idx < 1536; idx += 256) {
        int b = idx / 768, r = idx - b * 768;
        int g = r / 12, c = r - g * 12;
        float s = fcb_l[c];
        const float* tr = T + b * 3072 + g * 48;
        for (int k = 0; k < 48; ++k) s = fmaf(tr[k], fcw_l[k * 12 + c], s);
        X[g * 24 + b * 12 + c] = s;
    }
    __syncthreads();
    for (int idx = tid; idx < 768; idx += 256) {
        int g = idx / 12, c = idx - g * 12;
        float s = fc1b_l[c];
        const float* xr = X + g * 24;
        for (int k = 0; k < 24; ++k) s = fmaf(xr[k], fc1w_l[k * 12 + c], s);
        Y[idx] = s;
    }
    __syncthreads();
    if (tid < 12) {
        float s = 0.f, ss = 0.f;
        for (int g = 0; g < 64; ++g) { float v = Y[g * 12 + tid]; s += v; ss += v * v; }
        float mu = s * (1.f / 64), var = ss * (1.f / 64) - mu * mu;
        float sc_ = rsqrtf(var + 1e-5f) * gf1_l[tid];
        st2[tid] = sc_;
        st2[12 + tid] = bf1_l[tid] - mu * sc_;
    }
    __syncthreads();
    if (tid < 64) {
        float s = fc2b_l[0];
        for (int k = 0; k < 12; ++k) {
            float v = fmaf(Y[tid * 12 + k], st2[k], st2[12 + k]);
            v = v > 0.f ? v : 0.f;
            s = fmaf(v, fc2w_l[k], s);
        }
        float sig = 1.f / (1.f + __expf(-s));
        if (*flag) ((u16*)out)[tid] = f2bf(sig);
        else       ((float*)out)[tid] = sig;
    }
}

extern "C" void kernel_launch(void* const* d_in, const int* in_sizes, int n_in,
                              void* d_out, int out_size, void* d_ws, size_t ws_size,
                              hipStream_t stream) {
    const void* xin[2]  = {d_in[0], d_in[1]};
    const int* ei[2]    = {(const int*)d_in[2], (const int*)d_in[3]};
    const int* batch[2] = {(const int*)d_in[4], (const int*)d_in[5]};

    // ---- workspace layout (~65.5 MB; validated rounds 4-5/8/10 against 256 MiB ws) ----
    char* ws = (char*)d_ws;
    u16*   Hb     = (u16*)(ws + 0);              // 2 x 10,240,000 (aliased as CSR staging buf)
    u16*   Ab     = (u16*)(ws + 20480000);       // 2 x 10,240,000
    float* es     = (float*)(ws + 40960000);     // 2 x 640,000
    float* ed     = (float*)(ws + 42240000);     // 2 x 640,000
    float* scw    = (float*)(ws + 43520000);     // 2 x 160,000
    int*   fill   = (int*)(ws + 43840000);       // 2 x 160,000
    int*   csrc   = (int*)(ws + 44160000);       // 2 x 10,240,000 (padded CSR, cap 64)
    float* wcvt   = (float*)(ws + 64640000);     //    240,000
    u16*   Wtb    = (u16*)(ws + 64880000);       //     98,304 (3x 128x128 bf16, transposed)
    float* zbase  = (float*)(ws + 64978304);
    float* bkt    = zbase;                       //  6*64*256 = 98304 floats (zeroed)
    float* pooled = zbase + 98304;               //  2*8192 floats (zeroed)
    int*   gcnt   = (int*)(zbase + 114688);      //  320 ints (2*NB, zeroed)
    float* gden   = zbase + 115008;              //  128 floats
    float* bnc    = zbase + 115136;              //  2*256
    float* Tall   = zbase + 115648;              //  6144
    int*   flag   = (int*)(zbase + 121792);

    // ---- weight conversion table ----
    static const int widx[28] = {6,7,8, 10,11,12, 14,15,16, 18,19,20, 23,24,25,
                                 21,26, 22,27, 28, 30,31, 32,33, 34,35, 36,37};
    static const int wn[28]   = {16384,128,128, 16384,128,128, 16384,128,128, 128,128,128,
                                 128,128,128, 48,48, 12,12, 128, 6144,48, 576,12, 288,12, 12,1};
    CvtArgs ca;
    float* wptr[28];
    {
        size_t off = 0;
        for (int i = 0; i < 28; ++i) {
            ca.src[i] = d_in[widx[i]];
            ca.dst[i] = wcvt + off;
            ca.n[i] = wn[i];
            wptr[i] = wcvt + off;
            off += wn[i];
        }
    }
    const float* asf[3] = {wptr[1], wptr[4], wptr[7]};
    const float* adf[3] = {wptr[2], wptr[5], wptr[8]};
    const float* gf[3]  = {wptr[9], wptr[10], wptr[11]};
    const float* bef[3] = {wptr[12], wptr[13], wptr[14]};
    const float *gbi = wptr[15], *bbi = wptr[16], *gf1 = wptr[17], *bf1 = wptr[18];
    const float *attw = wptr[19], *fciw = wptr[20], *fcib = wptr[21];
    const float *fcw = wptr[22], *fcb = wptr[23], *fc1w = wptr[24], *fc1b = wptr[25];
    const float *fc2w = wptr[26], *fc2b = wptr[27];

    detect_k<<<1, 256, 0, stream>>>((const u16*)d_in[0], flag);
    cvt_k<<<28, 256, 0, stream>>>(ca, flag);
    wtb_k<<<3, 256, 0, stream>>>(wcvt, Wtb);
    // zero bkt + pooled + gcnt in one memset
    (void)hipMemsetAsync(zbase, 0, (98304 + 16384 + 320) * sizeof(float), stream);

    // fused two-branch CSR build (staging buf aliases Hb: dead until matmul l=0 writes it)
    bucket_k<<<1000, 256, 0, stream>>>(ei[0], ei[1], gcnt, (int2*)Hb);
    build_k<<<2 * NB, 256, 0, stream>>>(gcnt, (const int2*)Hb, fill, csrc);

    for (int l = 0; l < 3; ++l) {
        matmul_mfma_k<<<2500, 128, 0, stream>>>(xin[0], xin[1], Ab, l == 0 ? 0 : 1, flag,
                                                bnc, Wtb + l * 16384, asf[l], adf[l],
                                                Hb, es, ed);
        agg_k<<<20000, 256, 0, stream>>>(Hb, es, ed, fill, csrc, Ab, bkt, l);
        bnconst_k<<<2, 256, 0, stream>>>(bkt, l, gf[l], bef[l], bnc);
    }
    pool_score_k<<<20000, 256, 0, stream>>>(Ab, bnc, attw, scw);
    pool_den_k<<<128, 256, 0, stream>>>(scw, batch[0], batch[1], gden);
    pool_accum2_k<<<1250, 256, 0, stream>>>(Ab, scw, batch[0], batch[1], gden, bnc, pooled);
    headA_k<<<128, 256, 0, stream>>>(pooled, fciw, fcib, Tall);
    headB_k<<<1, 256, 0, stream>>>(Tall, gbi, bbi, fcw, fcb, fc1w, fc1b, gf1, bf1,
                                   fc2w, fc2b, d_out, flag);
}

// Round 12
// 555.900 us; speedup vs baseline: 1.0812x; 1.0812x over previous
//
#include <hip/hip_runtime.h>

#define NN 40000
#define EE 512000
#define NB 157      // dst buckets per branch: d>>8, 256 nodes per bucket
#define BCAP 8000   // pairs per bucket (avg 3277, std ~57); 2*157*8000*8 = 20.1 MB <= |Hb2|

typedef unsigned short u16;
typedef __attribute__((ext_vector_type(8))) short bf16x8;
typedef __attribute__((ext_vector_type(4))) float f32x4;

__device__ __forceinline__ float bf2f(u16 u) { return __uint_as_float(((unsigned)u) << 16); }
__device__ __forceinline__ u16 f2bf(float f) {
    unsigned u = __float_as_uint(f);
    u += 0x7FFFu + ((u >> 16) & 1u);
    return (u16)(u >> 16);
}
__device__ __forceinline__ unsigned pack2(float a, float b) {
    return (unsigned)f2bf(a) | ((unsigned)f2bf(b) << 16);
}
__device__ __forceinline__ float lrelu(float t) { return t > 0.f ? t : 0.2f * t; }

// ---------------- dtype detection ----------------
__global__ __launch_bounds__(256) void detect_k(const u16* __restrict__ x, int* __restrict__ flag) {
    int t = threadIdx.x;
    int cnt = 0;
    for (int j = 0; j < 8; ++j) {
        float v = bf2f(x[(t * 8 + j) * 2]);
        float a = fabsf(v);
        if (a >= 0.00390625f && a <= 256.0f) cnt++;
    }
    __shared__ int sh[256];
    sh[t] = cnt;
    __syncthreads();
    for (int off = 128; off > 0; off >>= 1) {
        if (t < off) sh[t] += sh[t + off];
        __syncthreads();
    }
    if (t == 0) flag[0] = (sh[0] > 1024) ? 1 : 0;
}

// ---------------- weight conversion ----------------
struct CvtArgs {
    const void* src[28];
    float* dst[28];
    int n[28];
};

__global__ __launch_bounds__(256) void cvt_k(CvtArgs a, const int* __restrict__ flag) {
    int b = blockIdx.x;
    int n = a.n[b];
    float* d = a.dst[b];
    if (*flag) {
        const u16* p = (const u16*)a.src[b];
        for (int i = threadIdx.x; i < n; i += 256) d[i] = bf2f(p[i]);
    } else {
        const float* p = (const float*)a.src[b];
        for (int i = threadIdx.x; i < n; i += 256) d[i] = p[i];
    }
}

// transpose the 3 GAT weight matrices to bf16 Wt[n][k] for MFMA B-operand
__global__ __launch_bounds__(256) void wtb_k(const float* __restrict__ wcvt, u16* __restrict__ Wtb) {
    int l = blockIdx.x;
    const float* W = wcvt + l * 16640;  // W_l at stride 16384+128+128
    u16* D = Wtb + l * 16384;
    for (int i = threadIdx.x; i < 16384; i += 256) {
        int n = i >> 7, k = i & 127;
        D[i] = f2bf(W[k * 128 + n]);
    }
}

// ---------------- two-phase bucketed CSR build, both branches fused ----------------
__global__ __launch_bounds__(256) void bucket_k(const int* __restrict__ ei1,
                                                const int* __restrict__ ei2,
                                                int* __restrict__ gcnt,
                                                int2* __restrict__ buf) {
    __shared__ int lh[NB];
    __shared__ int lbase[NB];
    __shared__ int loff[NB];
    int branch = blockIdx.x >= 500;
    int blk = blockIdx.x - (branch ? 500 : 0);
    const int* ei = branch ? ei2 : ei1;
    int gb0 = branch * NB;
    int tid = threadIdx.x;
    for (int i = tid; i < NB; i += 256) lh[i] = 0;
    __syncthreads();
    int e0 = blk * 1024 + tid;
    int sv[4], dv[4], bv[4];
#pragma unroll
    for (int j = 0; j < 4; ++j) {
        int e = e0 + j * 256;
        int d = ei[EE + e];
        int s = ei[e];
        if ((unsigned)d >= NN) d = -1;   // drop invalid dst
        if ((unsigned)s >= NN) s = 0;    // sanitize invalid src
        dv[j] = d;
        sv[j] = s;
        bv[j] = d >> 8;
        if (d >= 0 && (unsigned)bv[j] < NB) atomicAdd(&lh[bv[j]], 1);
        else dv[j] = -1;
    }
    __syncthreads();
    for (int i = tid; i < NB; i += 256) {
        int c = lh[i];
        lbase[i] = c ? atomicAdd(&gcnt[gb0 + i], c) : 0;
        loff[i] = 0;
    }
    __syncthreads();
#pragma unroll
    for (int j = 0; j < 4; ++j) {
        if (dv[j] >= 0) {
            int b = bv[j];
            int p = lbase[b] + atomicAdd(&loff[b], 1);
            if ((unsigned)p < BCAP) buf[(size_t)(gb0 + b) * BCAP + p] = (int2){sv[j], dv[j]};
        }
    }
}

__global__ __launch_bounds__(256) void build_k(const int* __restrict__ gcnt,
                                               const int2* __restrict__ buf,
                                               int* __restrict__ fill,
                                               int* __restrict__ csrc) {
    __shared__ int lf[256];
    int branch = blockIdx.x >= NB;
    int b = blockIdx.x - (branch ? NB : 0);
    int tid = threadIdx.x;
    lf[tid] = 0;
    __syncthreads();
    int n = gcnt[branch * NB + b];
    if (n < 0) n = 0;
    if (n > BCAP) n = BCAP;
    int d0 = b << 8;
    size_t soff = (size_t)branch * NN;
    const int2* bp = buf + (size_t)(branch * NB + b) * BCAP;
    for (int i = tid; i < n; i += 256) {
        int2 p = bp[i];
        unsigned loc = (unsigned)(p.y - d0);
        if (loc < 256u && (unsigned)p.y < NN && (unsigned)p.x < NN) {
            int pos = atomicAdd(&lf[loc], 1);
            if ((unsigned)pos < 64u) csrc[(soff + p.y) * 64 + pos] = p.x;
        }
    }
    __syncthreads();
    int d = d0 + tid;
    if (d < NN) fill[soff + d] = lf[tid];  // agg_k clamps to 64
}

// ---------------- MFMA matmul + fused BN(precomputed consts) + fused es/ed ----------------
// 256 threads / 64 rows / grid 1250 (round-10 best-measured geometry).
__global__ __launch_bounds__(256) void matmul_mfma_k(const void* __restrict__ X1,
                                                     const void* __restrict__ X2,
                                                     const u16* __restrict__ Abase,
                                                     int mode,
                                                     const int* __restrict__ flag,
                                                     const float* __restrict__ bnc,
                                                     const u16* __restrict__ Wtb,
                                                     const float* __restrict__ asf,
                                                     const float* __restrict__ adf,
                                                     u16* __restrict__ Hbase,
                                                     float* __restrict__ es, float* __restrict__ ed) {
    __shared__ u16 Xs[64 * 136];
    __shared__ float scs[128], shs[128];
    int tid = threadIdx.x;
    int branch = blockIdx.x >= 625;
    int blk = blockIdx.x - (branch ? 625 : 0);
    size_t boff = (size_t)branch * NN;
    size_t row0 = (size_t)blk * 64;
    if (mode == 1) {
        if (tid < 128) {
            scs[tid] = bnc[branch * 256 + tid];
            shs[tid] = bnc[branch * 256 + 128 + tid];
        }
        __syncthreads();
        const uint2* X2p = reinterpret_cast<const uint2*>(Abase + (boff + row0) * 128);
        for (int i = tid; i < 2048; i += 256) {
            uint2 p = X2p[i];
            int r = i >> 5, c0 = (i & 31) * 4;
            float v0 = fmaf(bf2f((u16)(p.x & 0xffffu)), scs[c0], shs[c0]);
            float v1 = fmaf(bf2f((u16)(p.x >> 16)), scs[c0 + 1], shs[c0 + 1]);
            float v2 = fmaf(bf2f((u16)(p.y & 0xffffu)), scs[c0 + 2], shs[c0 + 2]);
            float v3 = fmaf(bf2f((u16)(p.y >> 16)), scs[c0 + 3], shs[c0 + 3]);
            v0 = v0 > 0.f ? v0 : 0.f; v1 = v1 > 0.f ? v1 : 0.f;
            v2 = v2 > 0.f ? v2 : 0.f; v3 = v3 > 0.f ? v3 : 0.f;
            unsigned* dst = (unsigned*)(Xs + r * 136 + c0);
            dst[0] = pack2(v0, v1);
            dst[1] = pack2(v2, v3);
        }
    } else {
        const void* Xv = branch ? X2 : X1;
        if (*flag) {
            const uint2* X2p = reinterpret_cast<const uint2*>((const u16*)Xv + row0 * 128);
            for (int i = tid; i < 2048; i += 256) {
                uint2 p = X2p[i];
                int r = i >> 5, c0 = (i & 31) * 4;
                unsigned* dst = (unsigned*)(Xs + r * 136 + c0);
                dst[0] = p.x;
                dst[1] = p.y;
            }
        } else {
            const float4* X4 = reinterpret_cast<const float4*>((const float*)Xv + row0 * 128);
            for (int i = tid; i < 2048; i += 256) {
                float4 v = X4[i];
                int r = i >> 5, c0 = (i & 31) * 4;
                unsigned* dst = (unsigned*)(Xs + r * 136 + c0);
                dst[0] = pack2(v.x, v.y);
                dst[1] = pack2(v.z, v.w);
            }
        }
    }
    __syncthreads();
    int w = tid >> 6, l = tid & 63;
    int q = l >> 4, c = l & 15;
    int mrow = w * 16;
    f32x4 acc[8];
#pragma unroll
    for (int t = 0; t < 8; ++t) acc[t] = (f32x4){0.f, 0.f, 0.f, 0.f};
#pragma unroll
    for (int ks = 0; ks < 4; ++ks) {
        int k0 = ks * 32;
        bf16x8 afrag = *(const bf16x8*)(Xs + (mrow + c) * 136 + k0 + q * 8);
#pragma unroll
        for (int t = 0; t < 8; ++t) {
            bf16x8 bfrag = *(const bf16x8*)(Wtb + (t * 16 + c) * 128 + k0 + q * 8);
            acc[t] = __builtin_amdgcn_mfma_f32_16x16x32_bf16(afrag, bfrag, acc[t], 0, 0, 0);
        }
    }
    // es/ed: per-head partial sums over this lane's cols, then 16-lane xor-reduce
    float esp[4][4] = {}, edp[4][4] = {};
#pragma unroll
    for (int t = 0; t < 8; ++t) {
        float av = asf[t * 16 + c], dv = adf[t * 16 + c];
        int h = t >> 1;
#pragma unroll
        for (int r = 0; r < 4; ++r) {
            esp[h][r] = fmaf(acc[t][r], av, esp[h][r]);
            edp[h][r] = fmaf(acc[t][r], dv, edp[h][r]);
        }
    }
#pragma unroll
    for (int h = 0; h < 4; ++h)
#pragma unroll
        for (int r = 0; r < 4; ++r) {
            esp[h][r] += __shfl_xor(esp[h][r], 1, 64);
            esp[h][r] += __shfl_xor(esp[h][r], 2, 64);
            esp[h][r] += __shfl_xor(esp[h][r], 4, 64);
            esp[h][r] += __shfl_xor(esp[h][r], 8, 64);
            edp[h][r] += __shfl_xor(edp[h][r], 1, 64);
            edp[h][r] += __shfl_xor(edp[h][r], 2, 64);
            edp[h][r] += __shfl_xor(edp[h][r], 4, 64);
            edp[h][r] += __shfl_xor(edp[h][r], 8, 64);
        }
    if (c < 4) {
#pragma unroll
        for (int r = 0; r < 4; ++r) {
            size_t grow = boff + row0 + mrow + q * 4 + r;
            es[grow * 4 + c] = esp[c][r];
            ed[grow * 4 + c] = edp[c][r];
        }
    }
    // store C: scatter bf16 into LDS (reuse Xs as unpadded 64x128), then coalesced copy
    __syncthreads();
    u16* Cs = Xs;
#pragma unroll
    for (int t = 0; t < 8; ++t)
#pragma unroll
        for (int r = 0; r < 4; ++r)
            Cs[(mrow + q * 4 + r) * 128 + t * 16 + c] = f2bf(acc[t][r]);
    __syncthreads();
    uint2* yp = (uint2*)(Hbase + (boff + row0) * 128);
    const uint2* cs2 = (const uint2*)Cs;
    for (int i = tid; i < 2048; i += 256) yp[i] = cs2[i];
}

// ---------------- GAT aggregation + fused BN-stat accumulation; both branches ----------------
// Round-4 structure (batched loops with SEPARATE load phases for 8-deep MLP) plus a
// 4-wide middle tier: shrinks the serial scalar tail from avg ~6 edges to avg ~2.
// Edge order unchanged (ascending) -> bitwise-identical accumulation.
__global__ __launch_bounds__(256) void agg_k(const u16* __restrict__ hb, const float* __restrict__ es,
                                             const float* __restrict__ ed, const int* __restrict__ fill,
                                             const int* __restrict__ csrc, u16* __restrict__ Ab,
                                             float* __restrict__ bktbase, int l) {
    __shared__ float ss[512], qq[512];
    int gwid = (blockIdx.x * 256 + threadIdx.x) >> 6;  // 0..79999
    int branch = gwid >= NN;
    size_t srow = branch ? (size_t)NN : 0;
    int lane = threadIdx.x & 63;
    int deg = fill[gwid];
    if (deg > 64) deg = 64;
    if (deg < 0) deg = 0;
    size_t rs = (size_t)gwid * 64;
    int head = lane >> 4;
    float edn = ed[gwid * 4 + head];
    float acc0, acc1, den;
    {
        float w = __expf(lrelu(es[gwid * 4 + head] + edn));
        den = w;
        unsigned pv = ((const unsigned*)(hb + (size_t)gwid * 128))[lane];
        acc0 = w * bf2f((u16)(pv & 0xffffu));
        acc1 = w * bf2f((u16)(pv >> 16));
    }
    int i = 0;
    for (; i + 8 <= deg; i += 8) {
        int sv[8];
#pragma unroll
        for (int j = 0; j < 8; ++j) sv[j] = csrc[rs + i + j];
        float wv[8];
#pragma unroll
        for (int j = 0; j < 8; ++j) wv[j] = __expf(lrelu(es[(srow + sv[j]) * 4 + head] + edn));
        unsigned pv[8];
#pragma unroll
        for (int j = 0; j < 8; ++j) pv[j] = ((const unsigned*)(hb + (srow + sv[j]) * 128))[lane];
#pragma unroll
        for (int j = 0; j < 8; ++j) {
            den += wv[j];
            acc0 = fmaf(wv[j], bf2f((u16)(pv[j] & 0xffffu)), acc0);
            acc1 = fmaf(wv[j], bf2f((u16)(pv[j] >> 16)), acc1);
        }
    }
    if (i + 4 <= deg) {
        int sv[4];
#pragma unroll
        for (int j = 0; j < 4; ++j) sv[j] = csrc[rs + i + j];
        float wv[4];
#pragma unroll
        for (int j = 0; j < 4; ++j) wv[j] = __expf(lrelu(es[(srow + sv[j]) * 4 + head] + edn));
        unsigned pv[4];
#pragma unroll
        for (int j = 0; j < 4; ++j) pv[j] = ((const unsigned*)(hb + (srow + sv[j]) * 128))[lane];
#pragma unroll
        for (int j = 0; j < 4; ++j) {
            den += wv[j];
            acc0 = fmaf(wv[j], bf2f((u16)(pv[j] & 0xffffu)), acc0);
            acc1 = fmaf(wv[j], bf2f((u16)(pv[j] >> 16)), acc1);
        }
        i += 4;
    }
    for (; i < deg; ++i) {
        int s = csrc[rs + i];
        float w = __expf(lrelu(es[(srow + s) * 4 + head] + edn));
        den += w;
        unsigned pv = ((const unsigned*)(hb + (srow + s) * 128))[lane];
        acc0 = fmaf(w, bf2f((u16)(pv & 0xffffu)), acc0);
        acc1 = fmaf(w, bf2f((u16)(pv >> 16)), acc1);
    }
    float inv = 1.0f / den;
    float v0 = acc0 * inv, v1 = acc1 * inv;
    ((unsigned*)Ab)[(size_t)gwid * 64 + lane] = (unsigned)f2bf(v0) | ((unsigned)f2bf(v1) << 16);
    int w = threadIdx.x >> 6;
    ss[w * 128 + 2 * lane] = v0;      ss[w * 128 + 2 * lane + 1] = v1;
    qq[w * 128 + 2 * lane] = v0 * v0; qq[w * 128 + 2 * lane + 1] = v1 * v1;
    __syncthreads();
    int t = threadIdx.x;
    float* dst = bktbase + (branch * 3 + l) * 16384 + (blockIdx.x & 63) * 256;
    if (t < 128) {
        atomicAdd(&dst[t], ss[t] + ss[128 + t] + ss[256 + t] + ss[384 + t]);
    } else {
        int f = t - 128;
        atomicAdd(&dst[t], qq[f] + qq[128 + f] + qq[256 + f] + qq[384 + f]);
    }
}

// ---------------- BN consts for layer l, both branches (grid 2) ----------------
__global__ __launch_bounds__(256) void bnconst_k(const float* __restrict__ bktbase, int l,
                                                 const float* __restrict__ gam,
                                                 const float* __restrict__ bet,
                                                 float* __restrict__ bnc) {
    __shared__ float red[256];
    int b = blockIdx.x;
    const float* bkt = bktbase + (b * 3 + l) * 16384;
    int tid = threadIdx.x;
    float s = 0.f;
    for (int k = 0; k < 64; ++k) s += bkt[k * 256 + tid];
    red[tid] = s;
    __syncthreads();
    if (tid < 128) {
        float mu = red[tid] * (1.0f / NN);
        float var = red[128 + tid] * (1.0f / NN) - mu * mu;
        float sc_ = rsqrtf(var + 1e-5f) * gam[tid];
        bnc[b * 256 + tid] = sc_;
        bnc[b * 256 + 128 + tid] = bet[tid] - mu * sc_;
    }
}

// ---------------- pooling: score (both branches; no atomics) ----------------
__global__ __launch_bounds__(256) void pool_score_k(const u16* __restrict__ Ab,
                                                    const float* __restrict__ bnc,
                                                    const float* __restrict__ attw,
                                                    float* __restrict__ scw) {
    int tid = threadIdx.x;
    int gwid = (blockIdx.x * 256 + tid) >> 6;
    int branch = gwid >= NN;
    const float* bncp = bnc + branch * 256;
    int lane = tid & 63;
    int f0 = 2 * lane, f1 = 2 * lane + 1;
    unsigned pv = ((const unsigned*)Ab)[(size_t)gwid * 64 + lane];
    float v0 = fmaf(bf2f((u16)(pv & 0xffffu)), bncp[f0], bncp[128 + f0]); v0 = v0 > 0.f ? v0 : 0.f;
    float v1 = fmaf(bf2f((u16)(pv >> 16)), bncp[f1], bncp[128 + f1]);     v1 = v1 > 0.f ? v1 : 0.f;
    float v = v0 * attw[f0] + v1 * attw[f1];
    for (int off = 1; off < 64; off <<= 1) v += __shfl_xor(v, off, 64);
    if (lane == 0) scw[gwid] = __expf(v);
}

__device__ __forceinline__ int lower_bound_dev(const int* __restrict__ b, int n, int v) {
    int lo = 0, hi = n;
    while (lo < hi) {
        int mid = (lo + hi) >> 1;
        if (b[mid] < v) lo = mid + 1; else hi = mid;
    }
    return lo;
}

// ---------------- pooling: per-graph denominator (grid 128) ----------------
__global__ __launch_bounds__(256) void pool_den_k(const float* __restrict__ scw,
                                                  const int* __restrict__ batch1,
                                                  const int* __restrict__ batch2,
                                                  float* __restrict__ gden) {
    int branch = blockIdx.x >= 64;
    int g = blockIdx.x - (branch ? 64 : 0);
    const int* batch = branch ? batch2 : batch1;
    const float* sc = scw + (size_t)branch * NN;
    int tid = threadIdx.x;
    int start = lower_bound_dev(batch, NN, g);
    int end = lower_bound_dev(batch, NN, g + 1);
    __shared__ float sh[256];
    float s = 0.f;
    for (int i = start + tid; i < end; i += 256) s += sc[i];
    sh[tid] = s;
    __syncthreads();
    for (int off = 128; off > 0; off >>= 1) {
        if (tid < off) sh[tid] += sh[tid + off];
        __syncthreads();
    }
    if (tid == 0) gden[blockIdx.x] = (sh[0] > 1e-30f) ? sh[0] : 1e-30f;
}

// ---------------- pooling: weighted accumulation (grid 1250) ----------------
__global__ __launch_bounds__(256) void pool_accum2_k(const u16* __restrict__ Ab,
                                                     const float* __restrict__ scw,
                                                     const int* __restrict__ batch1,
                                                     const int* __restrict__ batch2,
                                                     const float* __restrict__ gden,
                                                     const float* __restrict__ bnc,
                                                     float* __restrict__ pooled) {
    __shared__ float wsh[64];
    __shared__ int gsh[64];
    int branch = blockIdx.x >= 625;
    int blk = blockIdx.x - (branch ? 625 : 0);
    const int* batch = branch ? batch2 : batch1;
    size_t boff = (size_t)branch * NN;
    int r0 = blk * 64;
    int tid = threadIdx.x;
    if (tid < 64) {
        int g = batch[r0 + tid];
        if ((unsigned)g >= 64) g = 0;
        gsh[tid] = g;
        wsh[tid] = scw[boff + r0 + tid] / gden[branch * 64 + g];
    }
    __syncthreads();
    const float* bncp = bnc + branch * 256;
    float* poolp = pooled + (size_t)branch * 8192;
    int f = tid & 127, half = tid >> 7;
    float bs = bncp[f], bb = bncp[128 + f];
    float racc = 0.f;
    int curg = gsh[half];
    for (int r = half; r < 64; r += 2) {
        int g = gsh[r];
        if (g != curg) {
            atomicAdd(&poolp[curg * 128 + f], racc);
            racc = 0.f;
            curg = g;
        }
        float v = fmaf(bf2f(Ab[(boff + r0 + r) * 128 + f]), bs, bb);
        v = v > 0.f ? v : 0.f;
        racc = fmaf(wsh[r], v, racc);
    }
    atomicAdd(&poolp[curg * 128 + f], racc);
}

// ---------------- head A (grid 128) ----------------
__global__ __launch_bounds__(256) void headA_k(const float* __restrict__ pooled,
                                               const float* __restrict__ fciw, const float* __restrict__ fcib,
                                               float* __restrict__ Tall) {
    __shared__ float Wl[6144];
    __shared__ float Pl[128];
    int tid = threadIdx.x;
    int g = blockIdx.x;
    for (int i = tid; i < 6144; i += 256) Wl[i] = fciw[i];
    if (tid < 128) Pl[tid] = pooled[g * 128 + tid];
    __syncthreads();
    if (tid < 48) {
        float s = fcib[tid];
        for (int k = 0; k < 128; ++k) s = fmaf(Pl[k], Wl[k * 48 + tid], s);
        Tall[g * 48 + tid] = s;
    }
}

// ---------------- head B ----------------
__global__ __launch_bounds__(256) void headB_k(const float* __restrict__ Tall,
                                               const float* __restrict__ gbi, const float* __restrict__ bbi,
                                               const float* __restrict__ fcw, const float* __restrict__ fcb,
                                               const float* __restrict__ fc1w, const float* __restrict__ fc1b,
                                               const float* __restrict__ gf1, const float* __restrict__ bf1,
                                               const float* __restrict__ fc2w, const float* __restrict__ fc2b,
                                               void* __restrict__ out, const int* __restrict__ flag) {
    __shared__ float T[6144];
    __shared__ float X[64 * 24];
    __shared__ float Y[64 * 12];
    __shared__ float st[192];
    __shared__ float st2[24];
    __shared__ float wl[576 + 288 + 12 + 12 + 12 + 12 + 48 + 48 + 1];
    float* fcw_l  = wl;
    float* fc1w_l = wl + 576;
    float* fcb_l  = wl + 864;
    float* fc1b_l = wl + 876;
    float* gf1_l  = wl + 888;
    float* bf1_l  = wl + 900;
    float* gbi_l  = wl + 912;
    float* bbi_l  = wl + 960;
    float* fc2b_l = wl + 1008;
    __shared__ float fc2w_l[12];
    int tid = threadIdx.x;
    for (int i = tid; i < 6144; i += 256) T[i] = Tall[i];
    for (int i = tid; i < 576; i += 256) fcw_l[i] = fcw[i];
    for (int i = tid; i < 288; i += 256) fc1w_l[i] = fc1w[i];
    if (tid < 12) {
        fcb_l[tid] = fcb[tid]; fc1b_l[tid] = fc1b[tid];
        gf1_l[tid] = gf1[tid]; bf1_l[tid] = bf1[tid];
        fc2w_l[tid] = fc2w[tid];
    }
    if (tid < 48) { gbi_l[tid] = gbi[tid]; bbi_l[tid] = bbi[tid]; }
    if (tid == 0) fc2b_l[0] = fc2b[0];
    __syncthreads();
    if (tid < 96) {
        int b = tid / 48, c = tid - b * 48;
        float s = 0.f, ss = 0.f;
        for (int g = 0; g < 64; ++g) { float v = T[b * 3072 + g * 48 + c]; s += v; ss += v * v; }
        float mu = s * (1.f / 64), var = ss * (1.f / 64) - mu * mu;
        float sc_ = rsqrtf(var + 1e-5f) * gbi_l[c];
        st[tid] = sc_;
        st[96 + tid] = bbi_l[c] - mu * sc_;
    }
    __syncthreads();
    for (int i = tid; i < 6144; i += 256) {
        int b = i / 3072, c = i % 48;
        int col = b * 48 + c;
        float v = fmaf(T[i], st[col], st[96 + col]);
        T[i] = v > 0.f ? v : 0.f;
    }
    __syncthreads();
    for (int idx = tid; idx < 1536; idx += 256) {
        int b = idx / 768, r = idx - b * 768;
        int g = r / 12, c = r - g * 12;
        float s = fcb_l[c];
        const float* tr = T + b * 3072 + g * 48;
        for (int k = 0; k < 48; ++k) s = fmaf(tr[k], fcw_l[k * 12 + c], s);
        X[g * 24 + b * 12 + c] = s;
    }
    __syncthreads();
    for (int idx = tid; idx < 768; idx += 256) {
        int g = idx / 12, c = idx - g * 12;
        float s = fc1b_l[c];
        const float* xr = X + g * 24;
        for (int k = 0; k < 24; ++k) s = fmaf(xr[k], fc1w_l[k * 12 + c], s);
        Y[idx] = s;
    }
    __syncthreads();
    if (tid < 12) {
        float s = 0.f, ss = 0.f;
        for (int g = 0; g < 64; ++g) { float v = Y[g * 12 + tid]; s += v; ss += v * v; }
        float mu = s * (1.f / 64), var = ss * (1.f / 64) - mu * mu;
        float sc_ = rsqrtf(var + 1e-5f) * gf1_l[tid];
        st2[tid] = sc_;
        st2[12 + tid] = bf1_l[tid] - mu * sc_;
    }
    __syncthreads();
    if (tid < 64) {
        float s = fc2b_l[0];
        for (int k = 0; k < 12; ++k) {
            float v = fmaf(Y[tid * 12 + k], st2[k], st2[12 + k]);
            v = v > 0.f ? v : 0.f;
            s = fmaf(v, fc2w_l[k], s);
        }
        float sig = 1.f / (1.f + __expf(-s));
        if (*flag) ((u16*)out)[tid] = f2bf(sig);
        else       ((float*)out)[tid] = sig;
    }
}

extern "C" void kernel_launch(void* const* d_in, const int* in_sizes, int n_in,
                              void* d_out, int out_size, void* d_ws, size_t ws_size,
                              hipStream_t stream) {
    const void* xin[2]  = {d_in[0], d_in[1]};
    const int* ei[2]    = {(const int*)d_in[2], (const int*)d_in[3]};
    const int* batch[2] = {(const int*)d_in[4], (const int*)d_in[5]};

    // ---- workspace layout (~65.5 MB; validated rounds 4-5/8/10/11 against 256 MiB ws) ----
    char* ws = (char*)d_ws;
    u16*   Hb     = (u16*)(ws + 0);              // 2 x 10,240,000 (aliased as CSR staging buf)
    u16*   Ab     = (u16*)(ws + 20480000);       // 2 x 10,240,000
    float* es     = (float*)(ws + 40960000);     // 2 x 640,000
    float* ed     = (float*)(ws + 42240000);     // 2 x 640,000
    float* scw    = (float*)(ws + 43520000);     // 2 x 160,000
    int*   fill   = (int*)(ws + 43840000);       // 2 x 160,000
    int*   csrc   = (int*)(ws + 44160000);       // 2 x 10,240,000 (padded CSR, cap 64)
    float* wcvt   = (float*)(ws + 64640000);     //    240,000
    u16*   Wtb    = (u16*)(ws + 64880000);       //     98,304 (3x 128x128 bf16, transposed)
    float* zbase  = (float*)(ws + 64978304);
    float* bkt    = zbase;                       //  6*64*256 = 98304 floats (zeroed)
    float* pooled = zbase + 98304;               //  2*8192 floats (zeroed)
    int*   gcnt   = (int*)(zbase + 114688);      //  320 ints (2*NB, zeroed)
    float* gden   = zbase + 115008;              //  128 floats
    float* bnc    = zbase + 115136;              //  2*256
    float* Tall   = zbase + 115648;              //  6144
    int*   flag   = (int*)(zbase + 121792);

    // ---- weight conversion table ----
    static const int widx[28] = {6,7,8, 10,11,12, 14,15,16, 18,19,20, 23,24,25,
                                 21,26, 22,27, 28, 30,31, 32,33, 34,35, 36,37};
    static const int wn[28]   = {16384,128,128, 16384,128,128, 16384,128,128, 128,128,128,
                                 128,128,128, 48,48, 12,12, 128, 6144,48, 576,12, 288,12, 12,1};
    CvtArgs ca;
    float* wptr[28];
    {
        size_t off = 0;
        for (int i = 0; i < 28; ++i) {
            ca.src[i] = d_in[widx[i]];
            ca.dst[i] = wcvt + off;
            ca.n[i] = wn[i];
            wptr[i] = wcvt + off;
            off += wn[i];
        }
    }
    const float* asf[3] = {wptr[1], wptr[4], wptr[7]};
    const float* adf[3] = {wptr[2], wptr[5], wptr[8]};
    const float* gf[3]  = {wptr[9], wptr[10], wptr[11]};
    const float* bef[3] = {wptr[12], wptr[13], wptr[14]};
    const float *gbi = wptr[15], *bbi = wptr[16], *gf1 = wptr[17], *bf1 = wptr[18];
    const float *attw = wptr[19], *fciw = wptr[20], *fcib = wptr[21];
    const float *fcw = wptr[22], *fcb = wptr[23], *fc1w = wptr[24], *fc1b = wptr[25];
    const float *fc2w = wptr[26], *fc2b = wptr[27];

    detect_k<<<1, 256, 0, stream>>>((const u16*)d_in[0], flag);
    cvt_k<<<28, 256, 0, stream>>>(ca, flag);
    wtb_k<<<3, 256, 0, stream>>>(wcvt, Wtb);
    // zero bkt + pooled + gcnt in one memset
    (void)hipMemsetAsync(zbase, 0, (98304 + 16384 + 320) * sizeof(float), stream);

    // fused two-branch CSR build (staging buf aliases Hb: dead until matmul l=0 writes it)
    bucket_k<<<1000, 256, 0, stream>>>(ei[0], ei[1], gcnt, (int2*)Hb);
    build_k<<<2 * NB, 256, 0, stream>>>(gcnt, (const int2*)Hb, fill, csrc);

    for (int l = 0; l < 3; ++l) {
        matmul_mfma_k<<<1250, 256, 0, stream>>>(xin[0], xin[1], Ab, l == 0 ? 0 : 1, flag,
                                                bnc, Wtb + l * 16384, asf[l], adf[l],
                                                Hb, es, ed);
        agg_k<<<20000, 256, 0, stream>>>(Hb, es, ed, fill, csrc, Ab, bkt, l);
        bnconst_k<<<2, 256, 0, stream>>>(bkt, l, gf[l], bef[l], bnc);
    }
    pool_score_k<<<20000, 256, 0, stream>>>(Ab, bnc, attw, scw);
    pool_den_k<<<128, 256, 0, stream>>>(scw, batch[0], batch[1], gden);
    pool_accum2_k<<<1250, 256, 0, stream>>>(Ab, scw, batch[0], batch[1], gden, bnc, pooled);
    headA_k<<<128, 256, 0, stream>>>(pooled, fciw, fcib, Tall);
    headB_k<<<1, 256, 0, stream>>>(Tall, gbi, bbi, fcw, fcb, fc1w, fc1b, gf1, bf1,
                                   fc2w, fc2b, d_out, flag);
}